// Round 4
// baseline (429.944 us; speedup 1.0000x reference)
//
#include <hip/hip_runtime.h>
#include <hip/hip_bf16.h>
#include <math.h>

typedef unsigned short u16;
typedef __attribute__((ext_vector_type(4))) unsigned short u16x4;
typedef __attribute__((ext_vector_type(8))) unsigned short u16x8;
typedef __attribute__((ext_vector_type(8))) __bf16 bf16x8;
typedef __attribute__((ext_vector_type(4))) float f32x4;

#define BB 16
#define TSEQ 1024
#define CC 584          /* embed dim, also GEMM K (18*32 + 8 tail) */
#define KFULL 18        /* full 32-wide K iterations */
#define HH 8
#define DHD 73
#define NR (BB*TSEQ)    /* 16384 rows */
#define KPW 608         /* padded K for packed weight rows (19*32) */
#define DP 96           /* padded head dim (3*32) */
#define HD (HH*DP)      /* 768 */
#define NP3 640         /* padded N for final proj (5*128) */
/* exp(s*584^-0.5) == exp2(s * CEXP) */
#define CEXP 0.0596985934f

__device__ __forceinline__ u16 f2bf(float f) {
  union { float f; unsigned u; } c; c.f = f;
  unsigned v = c.u + 0x7fffu + ((c.u >> 16) & 1u);
  return (u16)(v >> 16);
}
__device__ __forceinline__ bf16x8 as_bf(u16x8 v) { return __builtin_bit_cast(bf16x8, v); }

// ---------------- pack kernels (rebuilt every launch; ws is poisoned) ----------------

// x [16384,584] f32 -> bf16 same layout
__global__ void pack_x_kernel(const float* __restrict__ x, u16* __restrict__ xb) {
  int idx = blockIdx.x * 256 + threadIdx.x;  // over 16384*73 u16x8 groups
  if (idx >= NR * (CC / 8)) return;
  const float* s = &x[(size_t)idx * 8];
  f32x4 a = *(const f32x4*)s;
  f32x4 b = *(const f32x4*)(s + 4);
  u16x8 o;
#pragma unroll
  for (int t = 0; t < 4; t++) { o[t] = f2bf(a[t]); o[4 + t] = f2bf(b[t]); }
  *(u16x8*)&xb[(size_t)idx * 8] = o;
}

// Wq/Wk/Wv [H,C,73] f32 -> wt [3][768][608] bf16: wt[w][h*96+d][c] = W[h][c][d], zero pads
__global__ void pack_w_kernel(const float* __restrict__ Wq, const float* __restrict__ Wk,
                              const float* __restrict__ Wv, u16* __restrict__ wt) {
  int idx = blockIdx.x * 256 + threadIdx.x;
  if (idx >= 3 * HD * KPW) return;
  int w   = idx / (HD * KPW);
  int rem = idx % (HD * KPW);
  int n = rem / KPW;
  int k = rem % KPW;
  int h = n / DP, d = n % DP;
  u16 val = 0;
  if (d < DHD && k < CC) {
    const float* W = (w == 0) ? Wq : ((w == 1) ? Wk : Wv);
    val = f2bf(W[((size_t)h * CC + k) * DHD + d]);
  }
  wt[idx] = val;
}

// Wp [584,584] f32 -> wpt [640][608] bf16: wpt[n][c'] = Wp[c'][n], zero pads
__global__ void pack_wp_kernel(const float* __restrict__ Wp, u16* __restrict__ wpt) {
  int idx = blockIdx.x * 256 + threadIdx.x;
  if (idx >= NP3 * KPW) return;
  int n = idx / KPW;
  int c = idx % KPW;
  u16 val = 0;
  if (n < CC && c < CC) val = f2bf(Wp[(size_t)c * CC + n]);
  wpt[idx] = val;
}

// ---------------- bf16 GEMM: C[m][n] = sum_{k<584} A[m][k]*Bt[n][k] ----------------
// blockIdx.x = n-tile (fast) so consecutive blocks share the A panel (L2 reuse).
// MODE 0: store bf16 row-major [M][768]
// MODE 1: transposed store for v: Cout[(b*768+n)*1024 + t]
// MODE 2: bias add, guard n < 584, store f32 [M][584]
// AF32:   A is f32 (convert in staging) else bf16.
template <int MODE, bool AF32>
__global__ __launch_bounds__(256) void gemm_bt_kernel(
    const void* __restrict__ Avoid, const u16* __restrict__ Bt,
    void* __restrict__ CoutV, const float* __restrict__ bias) {
  __shared__ u16 As[128 * 32];
  __shared__ u16 Bs[128 * 32];
  const int tid  = threadIdx.x;
  const int lane = tid & 63;
  const int wave = tid >> 6;
  const int m0 = blockIdx.y * 128;
  const int n0 = blockIdx.x * 128;
  const int wm = (wave >> 1) * 64;
  const int wn = (wave & 1) * 64;
  const int q15  = lane & 15;
  const int quad = lane >> 4;

  f32x4 acc[4][4];
#pragma unroll
  for (int i = 0; i < 4; i++)
#pragma unroll
    for (int j = 0; j < 4; j++) acc[i][j] = (f32x4){0.f, 0.f, 0.f, 0.f};

  const int r0 = tid >> 2;
  const int c0 = (tid & 3) * 8;
  const u16x8 zv = {0, 0, 0, 0, 0, 0, 0, 0};
  for (int kk = 0; kk < KFULL + 1; ++kk) {
    const int kb = kk * 32;
    u16x8 a0 = zv, a1 = zv;
    if (kk < KFULL || c0 == 0) {
      if (AF32) {
        const float* A = (const float*)Avoid;
        f32x4 f00 = *(const f32x4*)&A[(size_t)(m0 + r0) * CC + kb + c0];
        f32x4 f01 = *(const f32x4*)&A[(size_t)(m0 + r0) * CC + kb + c0 + 4];
        f32x4 f10 = *(const f32x4*)&A[(size_t)(m0 + r0 + 64) * CC + kb + c0];
        f32x4 f11 = *(const f32x4*)&A[(size_t)(m0 + r0 + 64) * CC + kb + c0 + 4];
#pragma unroll
        for (int t = 0; t < 4; t++) {
          a0[t] = f2bf(f00[t]); a0[4 + t] = f2bf(f01[t]);
          a1[t] = f2bf(f10[t]); a1[4 + t] = f2bf(f11[t]);
        }
      } else {
        const u16* A = (const u16*)Avoid;
        a0 = *(const u16x8*)&A[(size_t)(m0 + r0) * CC + kb + c0];
        a1 = *(const u16x8*)&A[(size_t)(m0 + r0 + 64) * CC + kb + c0];
      }
    }
    u16x8 b0 = *(const u16x8*)&Bt[(size_t)(n0 + r0) * KPW + kb + c0];
    u16x8 b1 = *(const u16x8*)&Bt[(size_t)(n0 + r0 + 64) * KPW + kb + c0];
    *(u16x8*)&As[r0 * 32 + c0]        = a0;
    *(u16x8*)&As[(r0 + 64) * 32 + c0] = a1;
    *(u16x8*)&Bs[r0 * 32 + c0]        = b0;
    *(u16x8*)&Bs[(r0 + 64) * 32 + c0] = b1;
    __syncthreads();
    bf16x8 af[4], bfr[4];
#pragma unroll
    for (int i = 0; i < 4; i++)
      af[i] = as_bf(*(const u16x8*)&As[(wm + i * 16 + q15) * 32 + quad * 8]);
#pragma unroll
    for (int j = 0; j < 4; j++)
      bfr[j] = as_bf(*(const u16x8*)&Bs[(wn + j * 16 + q15) * 32 + quad * 8]);
#pragma unroll
    for (int i = 0; i < 4; i++)
#pragma unroll
      for (int j = 0; j < 4; j++)
        acc[i][j] = __builtin_amdgcn_mfma_f32_16x16x32_bf16(af[i], bfr[j], acc[i][j], 0, 0, 0);
    __syncthreads();
  }

#pragma unroll
  for (int i = 0; i < 4; i++) {
#pragma unroll
    for (int j = 0; j < 4; j++) {
      const int row = m0 + wm + i * 16 + quad * 4;
      const int col = n0 + wn + j * 16 + q15;
      if (MODE == 0) {
        u16* Cout = (u16*)CoutV;
#pragma unroll
        for (int r = 0; r < 4; r++)
          Cout[(size_t)(row + r) * HD + col] = f2bf(acc[i][j][r]);
      } else if (MODE == 1) {
        u16* Cout = (u16*)CoutV;
        const int b  = row >> 10;
        const int tl = row & 1023;
        u16x4 pk;
#pragma unroll
        for (int r = 0; r < 4; r++) pk[r] = f2bf(acc[i][j][r]);
        *(u16x4*)&Cout[((size_t)(b * HD + col)) * TSEQ + tl] = pk;
      } else {
        if (col < CC) {
          float* Cout = (float*)CoutV;
          const float bv = bias[col];
#pragma unroll
          for (int r = 0; r < 4; r++)
            Cout[(size_t)(row + r) * CC + col] = acc[i][j][r] + bv;
        }
      }
    }
  }
}

// ---------------- flash attention: per (b,h,128-row q tile) ----------------
// Scores are bounded (|s*SCALE| < ~1), so softmax needs NO max subtraction:
// p = exp2(s*CEXP), row-sum deferred to epilogue -> zero shuffles in the loop.
// q,k: [B,T,768] bf16 ; vt: [B,768,T] bf16 ; out attn: [B,T,584] bf16 concat
__global__ __launch_bounds__(256, 3) void attn_kernel(
    const u16* __restrict__ qb, const u16* __restrict__ kb,
    const u16* __restrict__ vt, u16* __restrict__ attn) {
  __shared__ u16 smem[128 * 96 + 64 * 104 + 96 * 72];
  u16* Qs = smem;                       // [128][96]; later aliased as P [128][72]
  u16* Ks = smem + 128 * 96;            // [64][104] pitch-padded
  u16* Vs = smem + 128 * 96 + 64 * 104; // [96][72]  pitch-padded
  u16* Pl = smem;                       // P rows are wave-private (rows [32w,32w+32))

  const int tid  = threadIdx.x;
  const int lane = tid & 63;
  const int wave = tid >> 6;
  const int q15  = lane & 15;
  const int quad = lane >> 4;
  const int bid = blockIdx.x;
  const int b  = bid >> 6;
  const int h  = (bid >> 3) & 7;
  const int t0 = (bid & 7) * 128;

  // stage Q tile [128][96]
  for (int q = tid; q < 128 * 12; q += 256) {
    int row = q / 12, c8 = (q % 12) * 8;
    *(u16x8*)&Qs[row * 96 + c8] =
        *(const u16x8*)&qb[(size_t)(b * TSEQ + t0 + row) * HD + h * DP + c8];
  }
  __syncthreads();

  const int wq0 = wave * 32;
  bf16x8 aq[2][3];
#pragma unroll
  for (int m = 0; m < 2; m++)
#pragma unroll
    for (int kc = 0; kc < 3; kc++)
      aq[m][kc] = as_bf(*(const u16x8*)&Qs[(wq0 + m * 16 + q15) * 96 + kc * 32 + quad * 8]);

  f32x4 lsumv[2];
  f32x4 oacc[2][6];
#pragma unroll
  for (int m = 0; m < 2; m++) {
    lsumv[m] = (f32x4){0.f, 0.f, 0.f, 0.f};
#pragma unroll
    for (int jd = 0; jd < 6; jd++) oacc[m][jd] = (f32x4){0.f, 0.f, 0.f, 0.f};
  }

  for (int si = 0; si < 16; ++si) {
    const int s0 = si * 64;
    // stage K tile [64][96] (pitch 104)
    for (int q = tid; q < 64 * 12; q += 256) {
      int row = q / 12, c8 = (q % 12) * 8;
      *(u16x8*)&Ks[row * 104 + c8] =
          *(const u16x8*)&kb[(size_t)(b * TSEQ + s0 + row) * HD + h * DP + c8];
    }
    // stage V^T tile [96][64] (pitch 72)
    for (int q = tid; q < 96 * 8; q += 256) {
      int row = q / 8, c8 = (q % 8) * 8;
      *(u16x8*)&Vs[row * 72 + c8] =
          *(const u16x8*)&vt[((size_t)(b * HD + h * DP + row)) * TSEQ + s0 + c8];
    }
    __syncthreads();

    // S = Q K^T
    f32x4 sacc[2][4];
#pragma unroll
    for (int m = 0; m < 2; m++)
#pragma unroll
      for (int j = 0; j < 4; j++) sacc[m][j] = (f32x4){0.f, 0.f, 0.f, 0.f};
#pragma unroll
    for (int kc = 0; kc < 3; kc++) {
      bf16x8 bk[4];
#pragma unroll
      for (int j = 0; j < 4; j++)
        bk[j] = as_bf(*(const u16x8*)&Ks[(j * 16 + q15) * 104 + kc * 32 + quad * 8]);
#pragma unroll
      for (int m = 0; m < 2; m++)
#pragma unroll
        for (int j = 0; j < 4; j++)
          sacc[m][j] = __builtin_amdgcn_mfma_f32_16x16x32_bf16(aq[m][kc], bk[j], sacc[m][j], 0, 0, 0);
    }

    // p = exp2(s*CEXP); accumulate per-lane partial row-sums; store P to LDS
#pragma unroll
    for (int m = 0; m < 2; m++) {
#pragma unroll
      for (int j = 0; j < 4; j++) {
        f32x4 pv;
#pragma unroll
        for (int r = 0; r < 4; r++) pv[r] = exp2f(sacc[m][j][r] * CEXP);
        lsumv[m] += pv;
#pragma unroll
        for (int r = 0; r < 4; r++)
          Pl[(wq0 + m * 16 + quad * 4 + r) * 72 + j * 16 + q15] = f2bf(pv[r]);
      }
    }
    // no barrier: P rows are wave-private; compiler orders ds_write->ds_read

    // O += P V   (A = P from LDS, B = V^T rows)
#pragma unroll
    for (int kc = 0; kc < 2; kc++) {
      bf16x8 ap[2];
#pragma unroll
      for (int m = 0; m < 2; m++)
        ap[m] = as_bf(*(const u16x8*)&Pl[(wq0 + m * 16 + q15) * 72 + kc * 32 + quad * 8]);
#pragma unroll
      for (int jd = 0; jd < 6; jd++) {
        bf16x8 bv = as_bf(*(const u16x8*)&Vs[(jd * 16 + q15) * 72 + kc * 32 + quad * 8]);
#pragma unroll
        for (int m = 0; m < 2; m++)
          oacc[m][jd] = __builtin_amdgcn_mfma_f32_16x16x32_bf16(ap[m], bv, oacc[m][jd], 0, 0, 0);
      }
    }
    __syncthreads();
  }

  // epilogue: reduce row-sums across the 16 lanes of each quad-row group
#pragma unroll
  for (int m = 0; m < 2; m++) {
    const int trow = t0 + wq0 + m * 16 + quad * 4;
#pragma unroll
    for (int r = 0; r < 4; r++) {
      float s = lsumv[m][r];
#pragma unroll
      for (int off = 1; off < 16; off <<= 1) s += __shfl_xor(s, off);
      const float inv = 1.f / s;
#pragma unroll
      for (int jd = 0; jd < 5; jd++) {
        const int d = jd * 16 + q15;
        if (d < DHD)
          attn[(size_t)(b * TSEQ + trow + r) * CC + h * DHD + d] = f2bf(oacc[m][jd][r] * inv);
      }
    }
  }
}

// ---------------- launch ----------------

extern "C" void kernel_launch(void* const* d_in, const int* in_sizes, int n_in,
                              void* d_out, int out_size, void* d_ws, size_t ws_size,
                              hipStream_t stream) {
  const float* x   = (const float*)d_in[0];
  const float* mem = (const float*)d_in[1];
  const float* Wq  = (const float*)d_in[2];
  const float* Wk  = (const float*)d_in[3];
  const float* Wv  = (const float*)d_in[4];
  const float* Wp  = (const float*)d_in[5];
  const float* bp  = (const float*)d_in[6];
  float* out = (float*)d_out;

  char* ws = (char*)d_ws;
  const size_t SZ_XB  = (size_t)NR * CC * 2;     // 19,136,512
  const size_t SZ_WT  = (size_t)HD * KPW * 2;    //    933,888 per weight
  const size_t SZ_WPT = (size_t)NP3 * KPW * 2;   //    778,240
  const size_t SZ_QB  = (size_t)NR * HD * 2;     // 25,165,824

  u16* xb     = (u16*)(ws);                       // x as bf16; later aliased by attn_o
  u16* attn_o = (u16*)(ws);
  u16* wq_t   = (u16*)(ws + SZ_XB);
  u16* wk_t   = (u16*)(ws + SZ_XB + SZ_WT);
  u16* wv_t   = (u16*)(ws + SZ_XB + 2 * SZ_WT);
  u16* wp_t   = (u16*)(ws + SZ_XB + 3 * SZ_WT);
  u16* q_buf  = (u16*)(ws + SZ_XB + 3 * SZ_WT + SZ_WPT);
  u16* k_buf  = (u16*)(ws + SZ_XB + 3 * SZ_WT + SZ_WPT + SZ_QB);
  u16* vt_buf = (u16*)(ws + SZ_XB + 3 * SZ_WT + SZ_WPT + 2 * SZ_QB);
  // total ws use: 19.1 + 2.8 + 0.78 + 75.5 MB ~= 98.2 MB (same as round 3)

  (void)in_sizes; (void)n_in; (void)out_size; (void)ws_size;

  // packs
  pack_x_kernel<<<(NR * (CC / 8) + 255) / 256, 256, 0, stream>>>(x, xb);
  pack_w_kernel<<<(3 * HD * KPW + 255) / 256, 256, 0, stream>>>(Wq, Wk, Wv, wq_t);
  pack_wp_kernel<<<(NP3 * KPW + 255) / 256, 256, 0, stream>>>(Wp, wp_t);

  // q,k,v projections (n-tile fastest for A-panel L2 reuse)
  dim3 g1(HD / 128, NR / 128);
  gemm_bt_kernel<0, false><<<g1, 256, 0, stream>>>(xb,  wq_t, q_buf,  nullptr);
  gemm_bt_kernel<0, true ><<<g1, 256, 0, stream>>>(mem, wk_t, k_buf,  nullptr);
  gemm_bt_kernel<1, false><<<g1, 256, 0, stream>>>(xb,  wv_t, vt_buf, nullptr);

  // attention (writes attn_o, aliasing the now-dead xb)
  attn_kernel<<<BB * HH * (TSEQ / 128), 256, 0, stream>>>(q_buf, k_buf, vt_buf, attn_o);

  // output projection + bias -> f32 out
  dim3 g3(NP3 / 128, NR / 128);
  gemm_bt_kernel<2, false><<<g3, 256, 0, stream>>>(attn_o, wp_t, out, bp);
}

// Round 5
// 371.465 us; speedup vs baseline: 1.1574x; 1.1574x over previous
//
#include <hip/hip_runtime.h>
#include <hip/hip_bf16.h>
#include <math.h>

typedef unsigned short u16;
typedef __attribute__((ext_vector_type(4))) unsigned short u16x4;
typedef __attribute__((ext_vector_type(8))) unsigned short u16x8;
typedef __attribute__((ext_vector_type(8))) __bf16 bf16x8;
typedef __attribute__((ext_vector_type(4))) float f32x4;

#define BB 16
#define TSEQ 1024
#define CC 584          /* embed dim */
#define HH 8
#define DHD 73
#define NR (BB*TSEQ)    /* 16384 rows */
#define KPW 608         /* padded K (19*32) — uniform GEMM K-loop */
#define KIT 19
#define DP 96           /* padded head dim */
#define HD (HH*DP)      /* 768 */
#define NP3 640         /* padded N for final proj */
/* exp(s*584^-0.5) == exp2(s * CEXP); scores bounded -> no max subtraction */
#define CEXP 0.0596985934f

__device__ __forceinline__ u16 f2bf(float f) {
  union { float f; unsigned u; } c; c.f = f;
  unsigned v = c.u + 0x7fffu + ((c.u >> 16) & 1u);
  return (u16)(v >> 16);
}
__device__ __forceinline__ bf16x8 as_bf(u16x8 v) { return __builtin_bit_cast(bf16x8, v); }

/* async global->LDS, 16B/lane, LDS dst = wave-uniform base + lane*16 */
#define GLL16(g, l) __builtin_amdgcn_global_load_lds( \
    (const __attribute__((address_space(1))) void*)(g), \
    (__attribute__((address_space(3))) void*)(l), 16, 0, 0)

// ---------------- pack kernels (rebuilt every launch; ws is poisoned) ----------------

// x|mem [16384,584] f32 -> xmb [32768][608] bf16 zero-padded
__global__ void pack_xm_kernel(const float* __restrict__ x, const float* __restrict__ mem,
                               u16* __restrict__ xmb) {
  int idx = blockIdx.x * 256 + threadIdx.x;   // over 32768*76 u16x8 groups
  if (idx >= 2 * NR * (KPW / 8)) return;
  int row = idx / (KPW / 8);
  int c8  = (idx % (KPW / 8)) * 8;
  u16x8 o = {0, 0, 0, 0, 0, 0, 0, 0};
  if (c8 < CC) {  // 584 % 8 == 0, so groups are fully valid or fully pad
    const float* src = (row < NR) ? &x[(size_t)row * CC + c8]
                                  : &mem[(size_t)(row - NR) * CC + c8];
    f32x4 a = *(const f32x4*)src;
    f32x4 b = *(const f32x4*)(src + 4);
#pragma unroll
    for (int t = 0; t < 4; t++) { o[t] = f2bf(a[t]); o[4 + t] = f2bf(b[t]); }
  }
  *(u16x8*)&xmb[(size_t)row * KPW + c8] = o;
}

// Wq/Wk/Wv [H,C,73] f32 -> wt [3][768][608] bf16: wt[w][h*96+d][c] = W[h][c][d]
__global__ void pack_w_kernel(const float* __restrict__ Wq, const float* __restrict__ Wk,
                              const float* __restrict__ Wv, u16* __restrict__ wt) {
  int idx = blockIdx.x * 256 + threadIdx.x;
  if (idx >= 3 * HD * KPW) return;
  int w   = idx / (HD * KPW);
  int rem = idx % (HD * KPW);
  int n = rem / KPW;
  int k = rem % KPW;
  int h = n / DP, d = n % DP;
  u16 val = 0;
  if (d < DHD && k < CC) {
    const float* W = (w == 0) ? Wq : ((w == 1) ? Wk : Wv);
    val = f2bf(W[((size_t)h * CC + k) * DHD + d]);
  }
  wt[idx] = val;
}

// Wp [584,584] f32 -> wpt [640][608] bf16: wpt[n][c'] = Wp[c'][n]
__global__ void pack_wp_kernel(const float* __restrict__ Wp, u16* __restrict__ wpt) {
  int idx = blockIdx.x * 256 + threadIdx.x;
  if (idx >= NP3 * KPW) return;
  int n = idx / KPW;
  int c = idx % KPW;
  u16 val = 0;
  if (n < CC && c < CC) val = f2bf(Wp[(size_t)c * CC + n]);
  wpt[idx] = val;
}

// ---------------- bf16 GEMM (m97 structure): C[m][n] = sum_k A[m][k]*Bt[n][k] ----------
// A, Bt both bf16 with row pitch KPW (zero-padded); uniform 19-iter K-loop.
// Staging via global_load_lds width=16. Grid: x = m-tile (fast), y = n-tile.
// MODE 0: store bf16 row-major [M][768]
// MODE 1: transposed store for v: Cout[(b*768+n)*1024 + t]
// MODE 2: bias add, guard n < 584, store f32 [M][584]
template <int MODE>
__global__ __launch_bounds__(256) void gemm_bt_kernel(
    const u16* __restrict__ A, const u16* __restrict__ Bt,
    void* __restrict__ CoutV, const float* __restrict__ bias) {
  __shared__ u16 As[128 * 32];
  __shared__ u16 Bs[128 * 32];
  const int tid  = threadIdx.x;
  const int lane = tid & 63;
  const int wave = tid >> 6;
  const int m0 = blockIdx.x * 128;
  const int n0 = blockIdx.y * 128;
  const int wm = (wave >> 1) * 64;
  const int wn = (wave & 1) * 64;
  const int q15  = lane & 15;
  const int quad = lane >> 4;

  f32x4 acc[4][4];
#pragma unroll
  for (int i = 0; i < 4; i++)
#pragma unroll
    for (int j = 0; j < 4; j++) acc[i][j] = (f32x4){0.f, 0.f, 0.f, 0.f};

  const int r0 = tid >> 2;          // row covered by this thread, round 0
  const int c0 = (tid & 3) * 8;
  // wave-uniform LDS bases: round r covers rows [r*64, r*64+64)
  u16* asd0 = &As[wave * 512];
  u16* asd1 = &As[2048 + wave * 512];
  u16* bsd0 = &Bs[wave * 512];
  u16* bsd1 = &Bs[2048 + wave * 512];
  const u16* gA0 = &A[(size_t)(m0 + r0) * KPW + c0];
  const u16* gA1 = gA0 + (size_t)64 * KPW;
  const u16* gB0 = &Bt[(size_t)(n0 + r0) * KPW + c0];
  const u16* gB1 = gB0 + (size_t)64 * KPW;

  for (int kk = 0; kk < KIT; ++kk) {
    GLL16(gA0, asd0);
    GLL16(gA1, asd1);
    GLL16(gB0, bsd0);
    GLL16(gB1, bsd1);
    gA0 += 32; gA1 += 32; gB0 += 32; gB1 += 32;
    __syncthreads();
    bf16x8 af[4], bfr[4];
#pragma unroll
    for (int i = 0; i < 4; i++)
      af[i] = as_bf(*(const u16x8*)&As[(wm + i * 16 + q15) * 32 + quad * 8]);
#pragma unroll
    for (int j = 0; j < 4; j++)
      bfr[j] = as_bf(*(const u16x8*)&Bs[(wn + j * 16 + q15) * 32 + quad * 8]);
#pragma unroll
    for (int i = 0; i < 4; i++)
#pragma unroll
      for (int j = 0; j < 4; j++)
        acc[i][j] = __builtin_amdgcn_mfma_f32_16x16x32_bf16(af[i], bfr[j], acc[i][j], 0, 0, 0);
    __syncthreads();
  }

#pragma unroll
  for (int i = 0; i < 4; i++) {
#pragma unroll
    for (int j = 0; j < 4; j++) {
      const int row = m0 + wm + i * 16 + quad * 4;
      const int col = n0 + wn + j * 16 + q15;
      if (MODE == 0) {
        u16* Cout = (u16*)CoutV;
#pragma unroll
        for (int r = 0; r < 4; r++)
          Cout[(size_t)(row + r) * HD + col] = f2bf(acc[i][j][r]);
      } else if (MODE == 1) {
        u16* Cout = (u16*)CoutV;
        const int b  = row >> 10;
        const int tl = row & 1023;
        u16x4 pk;
#pragma unroll
        for (int r = 0; r < 4; r++) pk[r] = f2bf(acc[i][j][r]);
        *(u16x4*)&Cout[((size_t)(b * HD + col)) * TSEQ + tl] = pk;
      } else {
        if (col < CC) {
          float* Cout = (float*)CoutV;
          const float bv = bias[col];
#pragma unroll
          for (int r = 0; r < 4; r++)
            Cout[(size_t)(row + r) * CC + col] = acc[i][j][r] + bv;
        }
      }
    }
  }
}

// ---------------- flash attention: per (b,h,128-row q tile) ----------------
// Computes S^T = K·Q^T per wave (rows=s, cols=q) so P stores to LDS are u16x4
// vectors; PV reads P as A-fragment from wave-private Pt [32 q][76 pitch].
// XCD swizzle: all 8 q-tiles of one (b,h) land on the same XCD (bid%8).
// q,k: [B,T,768] bf16 ; vt: [B,768,T] bf16 ; out attn: [16384][608] bf16, padded
__global__ __launch_bounds__(256, 3) void attn_kernel(
    const u16* __restrict__ qb, const u16* __restrict__ kb,
    const u16* __restrict__ vt, u16* __restrict__ attn) {
  __shared__ u16 smem[128 * 96 + 64 * 104 + 96 * 72];
  u16* Qs = smem;                       // [128][96]; later aliased by Pt
  u16* Ks = smem + 128 * 96;            // [64][104] pitch-padded
  u16* Vs = smem + 128 * 96 + 64 * 104; // [96][72]  pitch-padded
  u16* Pt = smem;                       // per-wave [32 q][pitch 76] s-major rows

  const int tid  = threadIdx.x;
  const int lane = tid & 63;
  const int wave = tid >> 6;
  const int q15  = lane & 15;
  const int quad = lane >> 4;
  // XCD-aware swizzle: bid%8 = XCD; group all 8 t-tiles of a (b,h) on one XCD
  const int bid  = blockIdx.x;
  const int loc  = bid >> 3;                      // 0..127
  const int pair = (bid & 7) * 16 + (loc >> 3);   // 0..127 = (b,h)
  const int b  = pair >> 3;
  const int h  = pair & 7;
  const int t0 = (loc & 7) * 128;

  // stage Q tile [128][96]
  for (int q = tid; q < 128 * 12; q += 256) {
    int row = q / 12, c8 = (q % 12) * 8;
    *(u16x8*)&Qs[row * 96 + c8] =
        *(const u16x8*)&qb[(size_t)(b * TSEQ + t0 + row) * HD + h * DP + c8];
  }
  // zero the pad cols 584..607 of this block's output rows (GLL needs clean pad)
  if (tid < 128) {
    const u16x8 z = {0, 0, 0, 0, 0, 0, 0, 0};
    size_t base = (size_t)(b * TSEQ + t0 + tid) * KPW + CC;
    *(u16x8*)&attn[base] = z;
    *(u16x8*)&attn[base + 8] = z;
    *(u16x8*)&attn[base + 16] = z;
  }
  __syncthreads();

  const int wq0 = wave * 32;
  // B-fragment of Q^T == A-fragment of Q: same register content, cached
  bf16x8 aq[2][3];
#pragma unroll
  for (int n = 0; n < 2; n++)
#pragma unroll
    for (int kc = 0; kc < 3; kc++)
      aq[n][kc] = as_bf(*(const u16x8*)&Qs[(wq0 + n * 16 + q15) * 96 + kc * 32 + quad * 8]);

  float lsum[2] = {0.f, 0.f};   // per-lane partial row-sum for q-col n*16+q15
  f32x4 oacc[2][6];
#pragma unroll
  for (int m = 0; m < 2; m++)
#pragma unroll
    for (int jd = 0; jd < 6; jd++) oacc[m][jd] = (f32x4){0.f, 0.f, 0.f, 0.f};

  u16* Ptw = &Pt[wave * 32 * 76];

  for (int si = 0; si < 16; ++si) {
    const int s0 = si * 64;
    // stage K tile [64][96] (pitch 104)
    for (int q = tid; q < 64 * 12; q += 256) {
      int row = q / 12, c8 = (q % 12) * 8;
      *(u16x8*)&Ks[row * 104 + c8] =
          *(const u16x8*)&kb[(size_t)(b * TSEQ + s0 + row) * HD + h * DP + c8];
    }
    // stage V^T tile [96][64] (pitch 72)
    for (int q = tid; q < 96 * 8; q += 256) {
      int row = q / 8, c8 = (q % 8) * 8;
      *(u16x8*)&Vs[row * 72 + c8] =
          *(const u16x8*)&vt[((size_t)(b * HD + h * DP + row)) * TSEQ + s0 + c8];
    }
    __syncthreads();

    // S^T = K Q^T  (A = K-frag, B = Q-frag); C rows = s (4 tiles), cols = q (2 tiles)
    f32x4 st[4][2];
#pragma unroll
    for (int mt = 0; mt < 4; mt++)
#pragma unroll
      for (int n = 0; n < 2; n++) st[mt][n] = (f32x4){0.f, 0.f, 0.f, 0.f};
#pragma unroll
    for (int kc = 0; kc < 3; kc++) {
      bf16x8 ak[4];
#pragma unroll
      for (int mt = 0; mt < 4; mt++)
        ak[mt] = as_bf(*(const u16x8*)&Ks[(mt * 16 + q15) * 104 + kc * 32 + quad * 8]);
#pragma unroll
      for (int mt = 0; mt < 4; mt++)
#pragma unroll
        for (int n = 0; n < 2; n++)
          st[mt][n] = __builtin_amdgcn_mfma_f32_16x16x32_bf16(ak[mt], aq[n][kc], st[mt][n], 0, 0, 0);
    }

    // p = exp2(s*CEXP); vectorized u16x4 store into Pt[q][s] (wave-private)
#pragma unroll
    for (int mt = 0; mt < 4; mt++) {
#pragma unroll
      for (int n = 0; n < 2; n++) {
        f32x4 pv;
#pragma unroll
        for (int r = 0; r < 4; r++) pv[r] = exp2f(st[mt][n][r] * CEXP);
        lsum[n] += (pv[0] + pv[1]) + (pv[2] + pv[3]);
        u16x4 pk;
#pragma unroll
        for (int r = 0; r < 4; r++) pk[r] = f2bf(pv[r]);
        *(u16x4*)&Ptw[(n * 16 + q15) * 76 + mt * 16 + quad * 4] = pk;
      }
    }
    // no barrier: Pt rows are wave-private; compiler orders ds_write->ds_read

    // O += P V  (A = P from Pt, vector b128 reads; B = V^T rows)
#pragma unroll
    for (int kc = 0; kc < 2; kc++) {
      bf16x8 ap[2];
#pragma unroll
      for (int m = 0; m < 2; m++)
        ap[m] = as_bf(*(const u16x8*)&Ptw[(m * 16 + q15) * 76 + kc * 32 + quad * 8]);
#pragma unroll
      for (int jd = 0; jd < 6; jd++) {
        bf16x8 bv = as_bf(*(const u16x8*)&Vs[(jd * 16 + q15) * 72 + kc * 32 + quad * 8]);
#pragma unroll
        for (int m = 0; m < 2; m++)
          oacc[m][jd] = __builtin_amdgcn_mfma_f32_16x16x32_bf16(ap[m], bv, oacc[m][jd], 0, 0, 0);
      }
    }
    __syncthreads();
  }

  // reduce row-sums: lane holds partial for q-col n*16+q15 over its quad's s-rows
  float lr[2];
#pragma unroll
  for (int n = 0; n < 2; n++) {
    float s = lsum[n];
    s += __shfl_xor(s, 16);
    s += __shfl_xor(s, 32);
    lr[n] = s;
  }

  // epilogue: oacc C-layout row q = m*16+quad*4+r, col d = jd*16+q15
#pragma unroll
  for (int m = 0; m < 2; m++) {
#pragma unroll
    for (int r = 0; r < 4; r++) {
      const float inv = 1.f / __shfl(lr[m], quad * 4 + r);
      const int trow = t0 + wq0 + m * 16 + quad * 4 + r;
#pragma unroll
      for (int jd = 0; jd < 5; jd++) {
        const int d = jd * 16 + q15;
        if (d < DHD)
          attn[(size_t)(b * TSEQ + trow) * KPW + h * DHD + d] = f2bf(oacc[m][jd][r] * inv);
      }
    }
  }
}

// ---------------- launch ----------------

extern "C" void kernel_launch(void* const* d_in, const int* in_sizes, int n_in,
                              void* d_out, int out_size, void* d_ws, size_t ws_size,
                              hipStream_t stream) {
  const float* x   = (const float*)d_in[0];
  const float* mem = (const float*)d_in[1];
  const float* Wq  = (const float*)d_in[2];
  const float* Wk  = (const float*)d_in[3];
  const float* Wv  = (const float*)d_in[4];
  const float* Wp  = (const float*)d_in[5];
  const float* bp  = (const float*)d_in[6];
  float* out = (float*)d_out;

  char* ws = (char*)d_ws;
  const size_t SZ_XMB = (size_t)2 * NR * KPW * 2;  // 39,845,888 (x rows, then mem rows)
  const size_t SZ_WT  = (size_t)HD * KPW * 2;      //    933,888 per weight
  const size_t SZ_WPT = (size_t)NP3 * KPW * 2;     //    778,240
  const size_t SZ_QB  = (size_t)NR * HD * 2;       // 25,165,824

  u16* xmb    = (u16*)(ws);            // [32768][608]; dead after proj GEMMs
  u16* attn_o = (u16*)(ws);            // alias: [16384][608] padded
  u16* wq_t   = (u16*)(ws + SZ_XMB);
  u16* wk_t   = (u16*)(ws + SZ_XMB + SZ_WT);
  u16* wv_t   = (u16*)(ws + SZ_XMB + 2 * SZ_WT);
  u16* wp_t   = (u16*)(ws + SZ_XMB + 3 * SZ_WT);
  u16* q_buf  = (u16*)(ws + SZ_XMB + 3 * SZ_WT + SZ_WPT);
  u16* k_buf  = (u16*)(ws + SZ_XMB + 3 * SZ_WT + SZ_WPT + SZ_QB);
  u16* vt_buf = (u16*)(ws + SZ_XMB + 3 * SZ_WT + SZ_WPT + 2 * SZ_QB);
  u16* memb   = xmb + (size_t)NR * KPW;
  // total ws use: 39.8 + 2.8 + 0.78 + 75.5 MB ~= 118.9 MB

  (void)in_sizes; (void)n_in; (void)out_size; (void)ws_size;

  // packs
  pack_xm_kernel<<<(2 * NR * (KPW / 8) + 255) / 256, 256, 0, stream>>>(x, mem, xmb);
  pack_w_kernel<<<(3 * HD * KPW + 255) / 256, 256, 0, stream>>>(Wq, Wk, Wv, wq_t);
  pack_wp_kernel<<<(NP3 * KPW + 255) / 256, 256, 0, stream>>>(Wp, wp_t);

  // q,k,v projections (m-tile fastest; B panel L2-resident, A streamed)
  dim3 g1(NR / 128, HD / 128);
  gemm_bt_kernel<0><<<g1, 256, 0, stream>>>(xmb,  wq_t, q_buf,  nullptr);
  gemm_bt_kernel<0><<<g1, 256, 0, stream>>>(memb, wk_t, k_buf,  nullptr);
  gemm_bt_kernel<1><<<g1, 256, 0, stream>>>(xmb,  wv_t, vt_buf, nullptr);

  // attention (writes attn_o with zeroed pad, aliasing the now-dead xmb)
  attn_kernel<<<BB * HH * (TSEQ / 128), 256, 0, stream>>>(q_buf, k_buf, vt_buf, attn_o);

  // output projection + bias -> f32 out
  dim3 g3(NR / 128, NP3 / 128);
  gemm_bt_kernel<2><<<g3, 256, 0, stream>>>(attn_o, wp_t, out, bp);
}